// Round 3
// baseline (823.068 us; speedup 1.0000x reference)
//
#include <hip/hip_runtime.h>
#include <hip/hip_bf16.h>
#include <stdint.h>

typedef __bf16 bf16;
typedef __attribute__((ext_vector_type(8))) __bf16 bf16x8;
typedef __attribute__((ext_vector_type(4))) float f32x4;

#define B_ 2
#define F_ 128
#define P_ 256
#define H_ 8
#define D_ 64
#define DIM_ 512
#define NROWS (B_*F_*P_)   // 65536

// async global->LDS, 16B per lane. LDS dest must be wave-uniform base + lane*16.
__device__ __forceinline__ void load_lds16(const void* g, void* l) {
  __builtin_amdgcn_global_load_lds(
      (__attribute__((address_space(1))) void*)(uintptr_t)g,
      (__attribute__((address_space(3))) void*)(uint32_t)(uintptr_t)l,
      16, 0, 0);
}

// fp32 -> bf16 cast, 8 elements/thread (n must be a multiple of 8)
__global__ void cvt_f32_bf16(const float* __restrict__ src, bf16* __restrict__ dst, int n)
{
  int i = (blockIdx.x * 256 + threadIdx.x) * 8;
  if (i < n) {
    float4 a = *(const float4*)(src + i);
    float4 b = *(const float4*)(src + i + 4);
    bf16x8 o;
    o[0] = (bf16)a.x; o[1] = (bf16)a.y; o[2] = (bf16)a.z; o[3] = (bf16)a.w;
    o[4] = (bf16)b.x; o[5] = (bf16)b.y; o[6] = (bf16)b.z; o[7] = (bf16)b.w;
    *(bf16x8*)(dst + i) = o;
  }
}

// W_o fp32 [512(he)][512(d)] -> wot bf16 [512(d)][512(he)]
__global__ void transpose_wo(const float* __restrict__ src, bf16* __restrict__ dst)
{
  int idx = blockIdx.x * 256 + threadIdx.x;
  int d = idx & 511, he = idx >> 9;
  dst[(size_t)d * 512 + he] = (bf16)src[(size_t)he * 512 + d];
}

// ---------------------------------------------------------------------------
// GEMM-BT: C[M x N] = A[M x K] * Bt[N x K]^T + bias[N]  (A,Bt bf16; bias fp32;
// C = OutT, fp32 accumulate). 128x128 tile, BK=32, 4 waves (2x2),
// each wave 64x64 = 4x4 tiles of 16x16. m97 structure.
// ---------------------------------------------------------------------------
#define BM 128
#define BN 128
#define BK 32

template <typename OutT>
__global__ __launch_bounds__(256, 2)
void gemm_bt_bias(const bf16* __restrict__ A, const bf16* __restrict__ Bt,
                  const float* __restrict__ bias, OutT* __restrict__ C,
                  int N, int K)
{
  __shared__ __align__(16) bf16 As[BM * BK];
  __shared__ __align__(16) bf16 Bs[BN * BK];

  const int t    = threadIdx.x;
  const int lane = t & 63;
  const int wave = t >> 6;
  const int wm   = wave & 1;
  const int wn   = wave >> 1;
  const int l16  = lane & 15;
  const int qd   = lane >> 4;

  const int mBase = blockIdx.y * BM;
  const int nBase = blockIdx.x * BN;

  f32x4 acc[4][4] = {};

  for (int k0 = 0; k0 < K; k0 += BK) {
    __syncthreads();
#pragma unroll
    for (int r = 0; r < 2; ++r) {
      int c = r * 256 + t;             // chunk id, 16B each
      int row = c >> 2;
      int col = (c & 3) << 3;
      load_lds16(A  + (size_t)(mBase + row) * K + k0 + col, As + c * 8);
      load_lds16(Bt + (size_t)(nBase + row) * K + k0 + col, Bs + c * 8);
    }
    __syncthreads();

    bf16x8 a[4], b[4];
#pragma unroll
    for (int i = 0; i < 4; ++i)
      a[i] = *(const bf16x8*)(As + (wm * 64 + i * 16 + l16) * BK + qd * 8);
#pragma unroll
    for (int j = 0; j < 4; ++j)
      b[j] = *(const bf16x8*)(Bs + (wn * 64 + j * 16 + l16) * BK + qd * 8);
#pragma unroll
    for (int i = 0; i < 4; ++i)
#pragma unroll
      for (int j = 0; j < 4; ++j)
        acc[i][j] = __builtin_amdgcn_mfma_f32_16x16x32_bf16(a[i], b[j], acc[i][j], 0, 0, 0);
  }

  // epilogue: D row = qd*4 + r, col = l16 within each 16x16 tile (m89/m91 layout)
#pragma unroll
  for (int j = 0; j < 4; ++j) {
    int coln = nBase + wn * 64 + j * 16 + l16;
    float bv = bias[coln];
#pragma unroll
    for (int i = 0; i < 4; ++i) {
      int rowm = mBase + wm * 64 + i * 16 + qd * 4;
#pragma unroll
      for (int r = 0; r < 4; ++r)
        C[(size_t)(rowm + r) * N + coln] = (OutT)(acc[i][j][r] + bv);
    }
  }
}

// ---------------------------------------------------------------------------
// Attention: per group, Q[128 x 64] attends over NK = NKB*128 keys.
// MODE 0 (frame): group=(b,p,h), keys = frames, row(i) = b*F*P + i*P + p
// MODE 1 (point): group=(b,f,h) x 2 q-blocks, keys = points, row(i) = (b*F+f)*P + i
// NO 1/sqrt(d) scaling (per reference). fp32 softmax, bf16 P round-trip in LDS.
// ---------------------------------------------------------------------------
template <int NKB, int MODE>
__global__ __launch_bounds__(256)
void attn_kernel(const bf16* __restrict__ qkv, bf16* __restrict__ outp)
{
  __shared__ __align__(16) bf16 lds[(2 + NKB) * 8192];
  bf16* Qs = lds;                     // [128][64]
  bf16* Ks = lds + 8192;              // [NK][64]
  bf16* Vt = lds + (1 + NKB) * 8192;  // [64][128] (per key-block)
  bf16* Pm = lds;                     // [128][128] overlay of Qs(+Ks)

  const int t    = threadIdx.x;
  const int lane = t & 63;
  const int wave = t >> 6;
  const int l16  = lane & 15;
  const int qd   = lane >> 4;

  const int bid = blockIdx.x;
  int h, q0, rowbase, rstride;
  if (MODE == 0) {
    h = bid & 7;
    int p = (bid >> 3) & (P_ - 1);
    int b = bid >> 11;
    rowbase = b * F_ * P_ + p; rstride = P_; q0 = 0;
  } else {
    int qb = bid & 1;
    h = (bid >> 1) & 7;
    int f = (bid >> 4) & (F_ - 1);
    int b = bid >> 11;
    rowbase = (b * F_ + f) * P_; rstride = 1; q0 = qb * 128;
  }

  // stage Q (qsel=0) and K (qsel=1) via async direct-to-LDS
#pragma unroll
  for (int r = 0; r < 4; ++r) {
    int c = r * 256 + t;
    int i = c >> 3, e = (c & 7) << 3;
    load_lds16(qkv + (size_t)(rowbase + (q0 + i) * rstride) * 1536 + h * 64 + e, Qs + c * 8);
  }
#pragma unroll
  for (int r = 0; r < 4 * NKB; ++r) {
    int c = r * 256 + t;
    int i = c >> 3, e = (c & 7) << 3;
    load_lds16(qkv + (size_t)(rowbase + i * rstride) * 1536 + 512 + h * 64 + e, Ks + c * 8);
  }
  __syncthreads();

  // S = Q K^T : wave owns 32 q-rows (all key columns)
  const int m0 = wave * 32;
  f32x4 acc[2][NKB * 8] = {};

  bf16x8 afr[2][2];
#pragma unroll
  for (int tm = 0; tm < 2; ++tm)
#pragma unroll
    for (int ks = 0; ks < 2; ++ks)
      afr[tm][ks] = *(const bf16x8*)(Qs + (m0 + tm * 16 + l16) * 64 + ks * 32 + qd * 8);

#pragma unroll
  for (int tn = 0; tn < NKB * 8; ++tn) {
    bf16x8 b0 = *(const bf16x8*)(Ks + (tn * 16 + l16) * 64 + qd * 8);
    bf16x8 b1 = *(const bf16x8*)(Ks + (tn * 16 + l16) * 64 + 32 + qd * 8);
#pragma unroll
    for (int tm = 0; tm < 2; ++tm) {
      acc[tm][tn] = __builtin_amdgcn_mfma_f32_16x16x32_bf16(afr[tm][0], b0, acc[tm][tn], 0, 0, 0);
      acc[tm][tn] = __builtin_amdgcn_mfma_f32_16x16x32_bf16(afr[tm][1], b1, acc[tm][tn], 0, 0, 0);
    }
  }

  // softmax over keys: row = m0 + tm*16 + qd*4 + r, cols spread over tn x l16
#pragma unroll
  for (int tm = 0; tm < 2; ++tm) {
#pragma unroll
    for (int r = 0; r < 4; ++r) {
      float m = -3.0e38f;
#pragma unroll
      for (int tn = 0; tn < NKB * 8; ++tn) m = fmaxf(m, acc[tm][tn][r]);
#pragma unroll
      for (int off = 1; off < 16; off <<= 1) m = fmaxf(m, __shfl_xor(m, off));
      float s = 0.0f;
#pragma unroll
      for (int tn = 0; tn < NKB * 8; ++tn) {
        float e0 = __expf(acc[tm][tn][r] - m);
        acc[tm][tn][r] = e0;
        s += e0;
      }
#pragma unroll
      for (int off = 1; off < 16; off <<= 1) s += __shfl_xor(s, off);
      float inv = 1.0f / s;
#pragma unroll
      for (int tn = 0; tn < NKB * 8; ++tn) acc[tm][tn][r] *= inv;
    }
  }

  // FA = P V, accumulated over key blocks of 128
  f32x4 facc[2][4] = {};
#pragma unroll
  for (int kb = 0; kb < NKB; ++kb) {
    __syncthreads();  // previous readers of Qs/Ks (or Pm/Vt) are done
    // write P block (bf16) into A-operand-friendly [128][128] layout
#pragma unroll
    for (int tm = 0; tm < 2; ++tm)
#pragma unroll
      for (int tj = 0; tj < 8; ++tj)
#pragma unroll
        for (int r = 0; r < 4; ++r)
          Pm[(m0 + tm * 16 + qd * 4 + r) * 128 + tj * 16 + l16] = (bf16)acc[tm][kb * 8 + tj][r];
    // stage V^T for this key block: Vt[e][g_local]
    {
      int iloc = t >> 1;
      int eh = (t & 1) * 32;
      const bf16* src = qkv + (size_t)(rowbase + (kb * 128 + iloc) * rstride) * 1536 + 1024 + h * 64 + eh;
#pragma unroll
      for (int jj = 0; jj < 4; ++jj) {
        bf16x8 v8 = *(const bf16x8*)(src + jj * 8);
#pragma unroll
        for (int j = 0; j < 8; ++j) Vt[(eh + jj * 8 + j) * 128 + iloc] = v8[j];
      }
    }
    __syncthreads();
#pragma unroll
    for (int ks = 0; ks < 4; ++ks) {
      bf16x8 pfr[2];
#pragma unroll
      for (int tm = 0; tm < 2; ++tm)
        pfr[tm] = *(const bf16x8*)(Pm + (m0 + tm * 16 + l16) * 128 + ks * 32 + qd * 8);
#pragma unroll
      for (int tn = 0; tn < 4; ++tn) {
        bf16x8 bv = *(const bf16x8*)(Vt + (tn * 16 + l16) * 128 + ks * 32 + qd * 8);
#pragma unroll
        for (int tm = 0; tm < 2; ++tm)
          facc[tm][tn] = __builtin_amdgcn_mfma_f32_16x16x32_bf16(pfr[tm], bv, facc[tm][tn], 0, 0, 0);
      }
    }
  }

  // store: row = q0 + local q, col = h*64 + e
#pragma unroll
  for (int tm = 0; tm < 2; ++tm)
#pragma unroll
    for (int tn = 0; tn < 4; ++tn)
#pragma unroll
      for (int r = 0; r < 4; ++r) {
        int iq = q0 + m0 + tm * 16 + qd * 4 + r;
        outp[(size_t)(rowbase + iq * rstride) * 512 + h * 64 + tn * 16 + l16] = (bf16)facc[tm][tn][r];
      }
}

extern "C" void kernel_launch(void* const* d_in, const int* in_sizes, int n_in,
                              void* d_out, int out_size, void* d_ws, size_t ws_size,
                              hipStream_t stream)
{
  (void)in_sizes; (void)n_in; (void)out_size; (void)ws_size;
  const float* x   = (const float*)d_in[0];   // [B,F,P,512] fp32
  const float* Wf  = (const float*)d_in[1];   // [3,8,64,512] fp32
  const float* bfb = (const float*)d_in[2];   // [1536] fp32
  const float* Wp  = (const float*)d_in[3];   // [3,8,64,8,64] fp32
  const float* bpb = (const float*)d_in[4];   // [1536] fp32
  const float* Wo  = (const float*)d_in[5];   // [8,64,512] fp32
  const float* bob = (const float*)d_in[6];   // [512] fp32
  float* out = (float*)d_out;                 // fp32 OUTPUT (per reference dtype)

  // workspace layout (bytes):
  //   [0, 192M)        qkv   (65536 x 1536 bf16)        reused for qkv2
  //   [192M, 256M)     fa    (65536 x 512 bf16)         first holds xb, then fa, then pa
  //   [256M, ...)      wfb (1.5M) | wpb (1.5M) | wot (0.5M)
  char* ws = (char*)d_ws;
  bf16* qkv = (bf16*)ws;
  bf16* fa  = (bf16*)(ws + (size_t)NROWS * 1536 * 2);
  bf16* xb  = fa;  // alias: xb is dead before fa is written
  char* wbase = ws + (size_t)NROWS * 1536 * 2 + (size_t)NROWS * 512 * 2;
  bf16* wfb = (bf16*)wbase;                        // 1536*512
  bf16* wpb = (bf16*)(wbase + 1536 * 512 * 2);     // 1536*512
  bf16* wot = (bf16*)(wbase + 2 * 1536 * 512 * 2); // 512*512

  // 0) fp32 -> bf16 conversions
  cvt_f32_bf16<<<(NROWS * 512) / (256 * 8), 256, 0, stream>>>(x, xb, NROWS * 512);
  cvt_f32_bf16<<<(1536 * 512) / (256 * 8), 256, 0, stream>>>(Wf, wfb, 1536 * 512);
  cvt_f32_bf16<<<(1536 * 512) / (256 * 8), 256, 0, stream>>>(Wp, wpb, 1536 * 512);
  transpose_wo<<<1024, 256, 0, stream>>>(Wo, wot);

  // 1) frame QKV: qkv = xb * W_f^T + b_f       [65536 x 1536]
  gemm_bt_bias<bf16><<<dim3(12, 512), 256, 0, stream>>>(xb, wfb, bfb, qkv, 1536, 512);
  // 2) frame attention -> fa                   [65536 x 512] (overwrites xb region)
  attn_kernel<1, 0><<<4096, 256, 0, stream>>>(qkv, fa);
  // 3) point QKV: qkv2 = fa * W_p^T + b_p      [65536 x 1536] (reuse qkv buf)
  gemm_bt_bias<bf16><<<dim3(12, 512), 256, 0, stream>>>(fa, wpb, bpb, qkv, 1536, 512);
  // 4) point attention -> pa                   [65536 x 512] (reuse fa buf)
  attn_kernel<2, 1><<<4096, 256, 0, stream>>>(qkv, fa);
  // 5) out projection: out = pa * Wot^T + b_o  [65536 x 512], fp32 out
  gemm_bt_bias<float><<<dim3(4, 512), 256, 0, stream>>>(fa, wot, bob, out, 512, 512);
}

// Round 4
// 772.420 us; speedup vs baseline: 1.0656x; 1.0656x over previous
//
#include <hip/hip_runtime.h>
#include <hip/hip_bf16.h>
#include <stdint.h>

typedef __bf16 bf16;
typedef __attribute__((ext_vector_type(8))) __bf16 bf16x8;
typedef __attribute__((ext_vector_type(4))) __bf16 bf16x4;
typedef __attribute__((ext_vector_type(4))) float f32x4;

#define B_ 2
#define F_ 128
#define P_ 256
#define H_ 8
#define D_ 64
#define DIM_ 512
#define NROWS (B_*F_*P_)   // 65536

// async global->LDS, 16B per lane. LDS dest must be wave-uniform base + lane*16.
__device__ __forceinline__ void load_lds16(const void* g, void* l) {
  __builtin_amdgcn_global_load_lds(
      (__attribute__((address_space(1))) void*)(uintptr_t)g,
      (__attribute__((address_space(3))) void*)(uint32_t)(uintptr_t)l,
      16, 0, 0);
}

// fp32 -> bf16 cast, 8 elements/thread (n must be a multiple of 8)
__global__ void cvt_f32_bf16(const float* __restrict__ src, bf16* __restrict__ dst, int n)
{
  int i = (blockIdx.x * 256 + threadIdx.x) * 8;
  if (i < n) {
    float4 a = *(const float4*)(src + i);
    float4 b = *(const float4*)(src + i + 4);
    bf16x8 o;
    o[0] = (bf16)a.x; o[1] = (bf16)a.y; o[2] = (bf16)a.z; o[3] = (bf16)a.w;
    o[4] = (bf16)b.x; o[5] = (bf16)b.y; o[6] = (bf16)b.z; o[7] = (bf16)b.w;
    *(bf16x8*)(dst + i) = o;
  }
}

// W_o fp32 [512(he)][512(d)] -> wot bf16 [512(d)][512(he)]
__global__ void transpose_wo(const float* __restrict__ src, bf16* __restrict__ dst)
{
  int idx = blockIdx.x * 256 + threadIdx.x;
  int d = idx & 511, he = idx >> 9;
  dst[(size_t)d * 512 + he] = (bf16)src[(size_t)he * 512 + d];
}

// ---------------------------------------------------------------------------
// GEMM-BT: C[M x N] = A[M x K] * Bt[N x K]^T + bias[N]  (A,Bt bf16; bias fp32;
// C = OutT, fp32 accumulate). 128x128 tile, BK=32, 4 waves (2x2).
// LDS layout XOR-swizzled: octet (m, koct) stored at m*32 + (koct^(m&3))*8 —
// turns the 8-way ds_read_b128 bank conflicts into 2-way (free).
// ---------------------------------------------------------------------------
#define BM 128
#define BN 128
#define BK 32

template <typename OutT>
__global__ __launch_bounds__(256, 2)
void gemm_bt_bias(const bf16* __restrict__ A, const bf16* __restrict__ Bt,
                  const float* __restrict__ bias, OutT* __restrict__ C,
                  int N, int K)
{
  __shared__ __align__(16) bf16 As[BM * BK];
  __shared__ __align__(16) bf16 Bs[BN * BK];

  const int t    = threadIdx.x;
  const int lane = t & 63;
  const int wave = t >> 6;
  const int wm   = wave & 1;
  const int wn   = wave >> 1;
  const int l16  = lane & 15;
  const int qd   = lane >> 4;

  const int mBase = blockIdx.y * BM;
  const int nBase = blockIdx.x * BN;

  f32x4 acc[4][4] = {};

  for (int k0 = 0; k0 < K; k0 += BK) {
    __syncthreads();
#pragma unroll
    for (int r = 0; r < 2; ++r) {
      int c = r * 256 + t;             // LDS slot id, 16B each
      int row = c >> 2;
      int col = (((c & 3) ^ (row & 3)) << 3);   // swizzled k-octet
      load_lds16(A  + (size_t)(mBase + row) * K + k0 + col, As + c * 8);
      load_lds16(Bt + (size_t)(nBase + row) * K + k0 + col, Bs + c * 8);
    }
    __syncthreads();

    bf16x8 a[4], b[4];
#pragma unroll
    for (int i = 0; i < 4; ++i) {
      int row = wm * 64 + i * 16 + l16;
      a[i] = *(const bf16x8*)(As + row * BK + ((qd ^ (row & 3)) << 3));
    }
#pragma unroll
    for (int j = 0; j < 4; ++j) {
      int row = wn * 64 + j * 16 + l16;
      b[j] = *(const bf16x8*)(Bs + row * BK + ((qd ^ (row & 3)) << 3));
    }
#pragma unroll
    for (int i = 0; i < 4; ++i)
#pragma unroll
      for (int j = 0; j < 4; ++j)
        acc[i][j] = __builtin_amdgcn_mfma_f32_16x16x32_bf16(a[i], b[j], acc[i][j], 0, 0, 0);
  }

  // epilogue: D row = qd*4 + r, col = l16 within each 16x16 tile
#pragma unroll
  for (int j = 0; j < 4; ++j) {
    int coln = nBase + wn * 64 + j * 16 + l16;
    float bv = bias[coln];
#pragma unroll
    for (int i = 0; i < 4; ++i) {
      int rowm = mBase + wm * 64 + i * 16 + qd * 4;
#pragma unroll
      for (int r = 0; r < 4; ++r)
        C[(size_t)(rowm + r) * N + coln] = (OutT)(acc[i][j][r] + bv);
    }
  }
}

// ---------------------------------------------------------------------------
// Attention v2: S^T = K·Q^T (C layout: row=key, col=q), softmax in registers,
// O^T = V^T·P^T. Q/K fragments loaded straight from global (b128, no LDS).
// LDS: Vt[64][VS] (V transposed, padded) + Pq[128][136] (wave-private P rows).
// One __syncthreads total. NKT = key tiles of 16 (8 frame / 16 point).
// ---------------------------------------------------------------------------
template <int NKT, int MODE, int VS>
__global__ __launch_bounds__(256, 2)
void attn2(const bf16* __restrict__ qkv, bf16* __restrict__ outp)
{
  __shared__ __align__(16) bf16 Vt[64 * VS];
  __shared__ __align__(16) bf16 Pq[128 * 136];

  const int t    = threadIdx.x;
  const int lane = t & 63;
  const int wave = t >> 6;
  const int l16  = lane & 15;
  const int qd   = lane >> 4;

  const int bid = blockIdx.x;
  int h, q0, rowbase, rstride;
  if (MODE == 0) {
    h = bid & 7;
    int p = (bid >> 3) & (P_ - 1);
    int b = bid >> 11;
    rowbase = b * F_ * P_ + p; rstride = P_; q0 = 0;
  } else {
    int qb = bid & 1;
    h = (bid >> 1) & 7;
    int f = (bid >> 4) & (F_ - 1);
    int b = bid >> 11;
    rowbase = (b * F_ + f) * P_; rstride = 1; q0 = qb * 128;
  }

  // ---- stage V^T into LDS: Vt[e][key], padded stride VS ----
#pragma unroll
  for (int p = 0; p < NKT / 8; ++p) {
    int key = p * 128 + (t >> 1);
    int eh  = (t & 1) * 32;
    const bf16* src = qkv + (size_t)(rowbase + key * rstride) * 1536 + 1024 + h * 64 + eh;
    bf16x8 v[4];
#pragma unroll
    for (int jj = 0; jj < 4; ++jj) v[jj] = *(const bf16x8*)(src + jj * 8);
#pragma unroll
    for (int jj = 0; jj < 4; ++jj)
#pragma unroll
      for (int j = 0; j < 8; ++j)
        Vt[(eh + jj * 8 + j) * VS + key] = v[jj][j];
  }

  // ---- Q fragments (wave owns q columns wave*32..+31), direct global ----
  const int qloc = wave * 32;
  bf16x8 qf[2][2];
#pragma unroll
  for (int qt = 0; qt < 2; ++qt)
#pragma unroll
    for (int ks = 0; ks < 2; ++ks)
      qf[qt][ks] = *(const bf16x8*)(qkv +
          (size_t)(rowbase + (q0 + qloc + qt * 16 + l16) * rstride) * 1536 +
          h * 64 + ks * 32 + qd * 8);

  // ---- S^T = K·Q^T : K fragments direct from global ----
  f32x4 sacc[NKT][2] = {};
#pragma unroll
  for (int tn = 0; tn < NKT; ++tn) {
    const bf16* krow = qkv + (size_t)(rowbase + (tn * 16 + l16) * rstride) * 1536 + 512 + h * 64;
    bf16x8 kf0 = *(const bf16x8*)(krow + qd * 8);
    bf16x8 kf1 = *(const bf16x8*)(krow + 32 + qd * 8);
#pragma unroll
    for (int qt = 0; qt < 2; ++qt) {
      sacc[tn][qt] = __builtin_amdgcn_mfma_f32_16x16x32_bf16(kf0, qf[qt][0], sacc[tn][qt], 0, 0, 0);
      sacc[tn][qt] = __builtin_amdgcn_mfma_f32_16x16x32_bf16(kf1, qf[qt][1], sacc[tn][qt], 0, 0, 0);
    }
  }

  // ---- softmax over keys (rows of S^T): in-lane (tn,r) + shfl over qd ----
#pragma unroll
  for (int qt = 0; qt < 2; ++qt) {
    float m = -3.0e38f;
#pragma unroll
    for (int tn = 0; tn < NKT; ++tn)
#pragma unroll
      for (int r = 0; r < 4; ++r) m = fmaxf(m, sacc[tn][qt][r]);
    m = fmaxf(m, __shfl_xor(m, 16));
    m = fmaxf(m, __shfl_xor(m, 32));
    float s = 0.0f;
#pragma unroll
    for (int tn = 0; tn < NKT; ++tn)
#pragma unroll
      for (int r = 0; r < 4; ++r) {
        float e0 = __expf(sacc[tn][qt][r] - m);
        sacc[tn][qt][r] = e0;
        s += e0;
      }
    s += __shfl_xor(s, 16);
    s += __shfl_xor(s, 32);
    float inv = 1.0f / s;
#pragma unroll
    for (int tn = 0; tn < NKT; ++tn)
#pragma unroll
      for (int r = 0; r < 4; ++r) sacc[tn][qt][r] *= inv;
  }

  // ---- O^T = V^T·P^T, key-halves of 128; Pq rows are wave-private ----
  f32x4 oacc[4][2] = {};
#pragma unroll
  for (int hf = 0; hf < NKT / 8; ++hf) {
    // pack P rows (4 consecutive keys per lane) into Pq[q][key_local], b64
#pragma unroll
    for (int qt = 0; qt < 2; ++qt)
#pragma unroll
      for (int tl = 0; tl < 8; ++tl) {
        int tn = hf * 8 + tl;
        bf16x4 pk;
#pragma unroll
        for (int r = 0; r < 4; ++r) pk[r] = (bf16)sacc[tn][qt][r];
        *(bf16x4*)(Pq + (qloc + qt * 16 + l16) * 136 + tl * 16 + qd * 4) = pk;
      }
    if (hf == 0) __syncthreads();   // Vt ready; Pq needs no cross-wave sync
#pragma unroll
    for (int ks = 0; ks < 4; ++ks) {
      bf16x8 pf[2];
#pragma unroll
      for (int qt = 0; qt < 2; ++qt)
        pf[qt] = *(const bf16x8*)(Pq + (qloc + qt * 16 + l16) * 136 + ks * 32 + qd * 8);
#pragma unroll
      for (int te = 0; te < 4; ++te) {
        bf16x8 vf = *(const bf16x8*)(Vt + (te * 16 + l16) * VS + hf * 128 + ks * 32 + qd * 8);
#pragma unroll
        for (int qt = 0; qt < 2; ++qt)
          oacc[te][qt] = __builtin_amdgcn_mfma_f32_16x16x32_bf16(vf, pf[qt], oacc[te][qt], 0, 0, 0);
      }
    }
  }

  // ---- store O^T: lane holds rows e=te*16+qd*4..+3, col q -> b64 stores ----
#pragma unroll
  for (int te = 0; te < 4; ++te)
#pragma unroll
    for (int qt = 0; qt < 2; ++qt) {
      int q = q0 + qloc + qt * 16 + l16;
      bf16x4 pk;
#pragma unroll
      for (int r = 0; r < 4; ++r) pk[r] = (bf16)oacc[te][qt][r];
      *(bf16x4*)(outp + (size_t)(rowbase + q * rstride) * 512 + h * 64 + te * 16 + qd * 4) = pk;
    }
}

extern "C" void kernel_launch(void* const* d_in, const int* in_sizes, int n_in,
                              void* d_out, int out_size, void* d_ws, size_t ws_size,
                              hipStream_t stream)
{
  (void)in_sizes; (void)n_in; (void)out_size; (void)ws_size;
  const float* x   = (const float*)d_in[0];   // [B,F,P,512] fp32
  const float* Wf  = (const float*)d_in[1];   // [3,8,64,512] fp32
  const float* bfb = (const float*)d_in[2];   // [1536] fp32
  const float* Wp  = (const float*)d_in[3];   // [3,8,64,8,64] fp32
  const float* bpb = (const float*)d_in[4];   // [1536] fp32
  const float* Wo  = (const float*)d_in[5];   // [8,64,512] fp32
  const float* bob = (const float*)d_in[6];   // [512] fp32
  float* out = (float*)d_out;                 // fp32 output

  char* ws = (char*)d_ws;
  bf16* qkv = (bf16*)ws;                                   // 65536x1536 (reused)
  bf16* fa  = (bf16*)(ws + (size_t)NROWS * 1536 * 2);      // 65536x512 (xb/fa/pa)
  bf16* xb  = fa;
  char* wbase = ws + (size_t)NROWS * 1536 * 2 + (size_t)NROWS * 512 * 2;
  bf16* wfb = (bf16*)wbase;
  bf16* wpb = (bf16*)(wbase + 1536 * 512 * 2);
  bf16* wot = (bf16*)(wbase + 2 * 1536 * 512 * 2);

  cvt_f32_bf16<<<(NROWS * 512) / (256 * 8), 256, 0, stream>>>(x, xb, NROWS * 512);
  cvt_f32_bf16<<<(1536 * 512) / (256 * 8), 256, 0, stream>>>(Wf, wfb, 1536 * 512);
  cvt_f32_bf16<<<(1536 * 512) / (256 * 8), 256, 0, stream>>>(Wp, wpb, 1536 * 512);
  transpose_wo<<<1024, 256, 0, stream>>>(Wo, wot);

  // 1) frame QKV
  gemm_bt_bias<bf16><<<dim3(12, 512), 256, 0, stream>>>(xb, wfb, bfb, qkv, 1536, 512);
  // 2) frame attention (keys = 128 frames)
  attn2<8, 0, 136><<<4096, 256, 0, stream>>>(qkv, fa);
  // 3) point QKV
  gemm_bt_bias<bf16><<<dim3(12, 512), 256, 0, stream>>>(fa, wpb, bpb, qkv, 1536, 512);
  // 4) point attention (keys = 256 points)
  attn2<16, 1, 272><<<4096, 256, 0, stream>>>(qkv, fa);
  // 5) out projection (fp32 out)
  gemm_bt_bias<float><<<dim3(4, 512), 256, 0, stream>>>(fa, wot, bob, out, 512, 512);
}